// Round 1
// baseline (183.087 us; speedup 1.0000x reference)
//
#include <hip/hip_runtime.h>

constexpr int POOL = 7;
constexpr int GRIDS = 2;
constexpr float SCALE = 0.0625f;

__global__ __launch_bounds__(256) void psroi_align_kernel(
    const float* __restrict__ x, const float* __restrict__ rois,
    float* __restrict__ out, int C, int H, int W, int K, int C_out)
{
    int idx = blockIdx.x * blockDim.x + threadIdx.x;
    int total = K * C_out * POOL * POOL;
    if (idx >= total) return;

    int pw = idx % POOL;
    int t = idx / POOL;
    int ph = t % POOL;
    t /= POOL;
    int c_out = t % C_out;
    int k = t / C_out;

    const float* roi = rois + k * 5;
    int b = (int)roi[0];
    float rx1 = roi[1] * SCALE - 0.5f;
    float ry1 = roi[2] * SCALE - 0.5f;
    float rx2 = roi[3] * SCALE - 0.5f;
    float ry2 = roi[4] * SCALE - 0.5f;
    float bsh = (ry2 - ry1) * (1.0f / POOL);
    float bsw = (rx2 - rx1) * (1.0f / POOL);

    int c_in = (c_out * POOL + ph) * POOL + pw;
    const float* plane = x + ((size_t)b * (size_t)C + (size_t)c_in) * (size_t)(H * W);

    float acc = 0.0f;
#pragma unroll
    for (int gy = 0; gy < GRIDS; ++gy) {
        float yy = ry1 + ((float)ph + ((float)gy + 0.5f) * (1.0f / GRIDS)) * bsh;
        bool vy = (yy >= -1.0f) && (yy <= (float)H);
        float yc = fmaxf(yy, 0.0f);
        int yl = min((int)yc, H - 1);          // floor: yc >= 0
        int yh = min(yl + 1, H - 1);
        float fy = (yl >= H - 1) ? 0.0f : (yc - (float)yl);
        float wyl = 1.0f - fy, wyh = fy;
#pragma unroll
        for (int gx = 0; gx < GRIDS; ++gx) {
            float xx = rx1 + ((float)pw + ((float)gx + 0.5f) * (1.0f / GRIDS)) * bsw;
            bool vx = (xx >= -1.0f) && (xx <= (float)W);
            float xc = fmaxf(xx, 0.0f);
            int xl = min((int)xc, W - 1);
            int xh = min(xl + 1, W - 1);
            float fx = (xl >= W - 1) ? 0.0f : (xc - (float)xl);
            float wxl = 1.0f - fx, wxh = fx;
            if (vy && vx) {
                const float* rl = plane + yl * W;
                const float* rh = plane + yh * W;
                acc += wyl * (wxl * rl[xl] + wxh * rl[xh])
                     + wyh * (wxl * rh[xl] + wxh * rh[xh]);
            }
        }
    }
    out[idx] = acc * 0.25f;
}

extern "C" void kernel_launch(void* const* d_in, const int* in_sizes, int n_in,
                              void* d_out, int out_size, void* d_ws, size_t ws_size,
                              hipStream_t stream) {
    const float* x    = (const float*)d_in[0];
    const float* rois = (const float*)d_in[1];
    float* out = (float*)d_out;

    const int C = 490, H = 100, W = 100;
    const int C_out = C / (POOL * POOL);      // 10
    int K = in_sizes[1] / 5;                  // 2048

    int total = K * C_out * POOL * POOL;      // == out_size
    int threads = 256;
    int blocks = (total + threads - 1) / threads;
    psroi_align_kernel<<<blocks, threads, 0, stream>>>(x, rois, out, C, H, W, K, C_out);
}

// Round 2
// 158.035 us; speedup vs baseline: 1.1585x; 1.1585x over previous
//
#include <hip/hip_runtime.h>

constexpr int POOL = 7;
constexpr int GRIDS = 2;
constexpr float SCALE = 0.0625f;

__global__ __launch_bounds__(256) void psroi_align_kernel(
    const float* __restrict__ x, const float* __restrict__ rois,
    float* __restrict__ out, int C, int H, int W, int K, int C_out)
{
    int idx = blockIdx.x * blockDim.x + threadIdx.x;
    int total = K * C_out * POOL * POOL;
    if (idx >= total) return;

    int pw = idx % POOL;
    int t = idx / POOL;
    int ph = t % POOL;
    t /= POOL;
    int c_out = t % C_out;
    int k = t / C_out;

    const float* roi = rois + k * 5;
    int b = (int)roi[0];
    float rx1 = roi[1] * SCALE - 0.5f;
    float ry1 = roi[2] * SCALE - 0.5f;
    float rx2 = roi[3] * SCALE - 0.5f;
    float ry2 = roi[4] * SCALE - 0.5f;
    float bsh = (ry2 - ry1) * (1.0f / POOL);
    float bsw = (rx2 - rx1) * (1.0f / POOL);

    int c_in = (c_out * POOL + ph) * POOL + pw;
    const float* plane = x + ((size_t)b * (size_t)C + (size_t)c_in) * (size_t)(H * W);

    // ---- per-axis interp pieces (computed up front, branch-free) ----
    int   yl[GRIDS], yh[GRIDS];
    float wyl[GRIDS], wyh[GRIDS];
    bool  vy[GRIDS];
    int   xl[GRIDS], xh[GRIDS];
    float wxl[GRIDS], wxh[GRIDS];
    bool  vx[GRIDS];

#pragma unroll
    for (int g = 0; g < GRIDS; ++g) {
        float yy = ry1 + ((float)ph + ((float)g + 0.5f) * (1.0f / GRIDS)) * bsh;
        vy[g] = (yy >= -1.0f) && (yy <= (float)H);
        float yc = fmaxf(yy, 0.0f);
        int lo = min((int)yc, H - 1);
        yl[g] = lo;
        yh[g] = min(lo + 1, H - 1);
        float fy = (lo >= H - 1) ? 0.0f : (yc - (float)lo);
        wyl[g] = 1.0f - fy;
        wyh[g] = fy;

        float xxv = rx1 + ((float)pw + ((float)g + 0.5f) * (1.0f / GRIDS)) * bsw;
        vx[g] = (xxv >= -1.0f) && (xxv <= (float)W);
        float xc = fmaxf(xxv, 0.0f);
        int lo2 = min((int)xc, W - 1);
        xl[g] = lo2;
        xh[g] = min(lo2 + 1, W - 1);
        float fx = (lo2 >= W - 1) ? 0.0f : (xc - (float)lo2);
        wxl[g] = 1.0f - fx;
        wxh[g] = fx;
    }

    // ---- issue ALL 16 loads unconditionally (clamped indices are in-bounds;
    //      invalid samples get weight 0) so they can be in flight together ----
    float v[4][4];
#pragma unroll
    for (int gy = 0; gy < GRIDS; ++gy) {
#pragma unroll
        for (int gx = 0; gx < GRIDS; ++gx) {
            const float* rl = plane + yl[gy] * W;
            const float* rh = plane + yh[gy] * W;
            int p = gy * GRIDS + gx;
            v[p][0] = rl[xl[gx]];
            v[p][1] = rl[xh[gx]];
            v[p][2] = rh[xl[gx]];
            v[p][3] = rh[xh[gx]];
        }
    }

    // ---- weighted reduction ----
    float acc = 0.0f;
#pragma unroll
    for (int gy = 0; gy < GRIDS; ++gy) {
#pragma unroll
        for (int gx = 0; gx < GRIDS; ++gx) {
            int p = gy * GRIDS + gx;
            float w = (vy[gy] && vx[gx]) ? 0.25f : 0.0f;
            float bil = wyl[gy] * (wxl[gx] * v[p][0] + wxh[gx] * v[p][1])
                      + wyh[gy] * (wxl[gx] * v[p][2] + wxh[gx] * v[p][3]);
            acc += w * bil;
        }
    }
    out[idx] = acc;
}

extern "C" void kernel_launch(void* const* d_in, const int* in_sizes, int n_in,
                              void* d_out, int out_size, void* d_ws, size_t ws_size,
                              hipStream_t stream) {
    const float* x    = (const float*)d_in[0];
    const float* rois = (const float*)d_in[1];
    float* out = (float*)d_out;

    const int C = 490, H = 100, W = 100;
    const int C_out = C / (POOL * POOL);      // 10
    int K = in_sizes[1] / 5;                  // 2048

    int total = K * C_out * POOL * POOL;      // == out_size
    int threads = 256;
    int blocks = (total + threads - 1) / threads;
    psroi_align_kernel<<<blocks, threads, 0, stream>>>(x, rois, out, C, H, W, K, C_out);
}